// Round 1
// baseline (83.939 us; speedup 1.0000x reference)
//
#include <hip/hip_runtime.h>

#define BDIM   256
#define GCHUNK 64      // gaussians per block (N=512 / 8 chunks)
#define SHN    27      // 9 SH coeffs * 3 channels

// Each block: 256 rays x 64 gaussians. Per-gaussian derived params staged in
// LDS (broadcast reads). Wave-vote skips the heavy SH/exp body when no lane's
// ray is inside the gaussian's 5-sigma ellipse (~83% of wave-iterations).
__global__ __launch_bounds__(BDIM, 4) void splat_kernel(
    const float* __restrict__ x,        // (B,2)
    const float* __restrict__ rgbsh,    // (N,9,3)
    const float* __restrict__ opacity,  // (N)
    const float* __restrict__ mu,       // (N,2)
    const float* __restrict__ scale,    // (N,2)
    const float* __restrict__ angle,    // (N)
    float* __restrict__ out,            // (B,3)
    int B, int N)
{
    __shared__ float4 gA[GCHUNK];            // gmx, gmy, Sx, Sy
    __shared__ float4 gB[GCHUNK];            // cos(a), sin(a), sigmoid(op), 0
    __shared__ float  gsh[GCHUNK][SHN];      // SH coeffs, [m*3+c]

    const int g0  = blockIdx.y * GCHUNK;
    const int tid = threadIdx.x;

    // ---- stage per-gaussian derived params ----
    if (tid < GCHUNK) {
        const int n = g0 + tid;
        const float S_MIN = 1.0f / 30.0f;
        const float S_MAX = 1.0f / 0.75f;
        float gmx = tanhf(mu[2 * n + 0]) * 1.05f;
        float gmy = tanhf(mu[2 * n + 1]) * 1.05f;
        float sx = fminf(fmaxf(scale[2 * n + 0], 0.0f), 1.0f) * (S_MAX - S_MIN) + S_MIN;
        float sy = fminf(fmaxf(scale[2 * n + 1], 0.0f), 1.0f) * (S_MAX - S_MIN) + S_MIN;
        gA[tid] = make_float4(gmx, gmy, sx, sy);
        float a = tanhf(angle[n]) * 3.1416f;
        float sa, ca;
        sincosf(a, &sa, &ca);
        float w0 = 1.0f / (1.0f + expf(-opacity[n]));
        gB[tid] = make_float4(ca, sa, w0, 0.0f);
    }
    for (int i = tid; i < GCHUNK * SHN; i += BDIM)
        gsh[0][i] = rgbsh[g0 * SHN + i];
    __syncthreads();

    // ---- per-ray setup ----
    const int b  = blockIdx.x * BDIM + tid;
    const int bb = (b < B) ? b : (B - 1);          // clamp for safe loads
    // xnorm = x/512*2 - 1  (exact pow2 scaling)
    float pnx = x[2 * bb + 0] * (1.0f / 256.0f) - 1.0f;
    float pny = x[2 * bb + 1] * (1.0f / 256.0f) - 1.0f;

    float accR = 0.0f, accG = 0.0f, accB = 0.0f;

    for (int j = 0; j < GCHUNK; ++j) {
        float4 p = gA[j];
        float vx = (pnx - p.x) * 256.0f;           // pixel-space offset
        float vy = (pny - p.y) * 256.0f;
        float sx = vx * p.z;
        float sy = vy * p.w;
        float t  = fmaf(sx, sx, sy * sy);          // == dist^2 (R is rotation)
        bool  v  = t < 25.0f;
        if (__any(v)) {
            if (v) {
                float4 q = gB[j];
                float c = q.x, s = q.y;
                // d2 via the rotated vector (matches reference path)
                float rx = c * sx - s * sy;
                float ry = fmaf(s, sx, c * sy);
                float d2 = fmaf(rx, rx, ry * ry);
                // view direction in gaussian frame; |vrot| ~= 1 so
                // sin(theta) = vrot_x, cos(theta) = vrot_y (no atan2 needed)
                float len = sqrtf(fmaf(vx, vx, vy * vy));
                float inv = 1.0f / (1e-10f + len);
                float vnx = vx * inv, vny = vy * inv;
                float s1 = c * vnx - s * vny;
                float c1 = fmaf(s, vnx, c * vny);
                // harmonics by angle addition
                float s2 = 2.0f * s1 * c1;
                float c2 = c1 * c1 - s1 * s1;
                float s3 = s2 * c1 + c2 * s1;
                float c3 = c2 * c1 - s2 * s1;
                float s4 = 2.0f * s2 * c2;
                float c4 = c2 * c2 - s2 * s2;
                const float* sh = gsh[j];
                float r  = sh[0], g = sh[1], bl = sh[2];
                r = fmaf(s1, sh[ 3], r);  g = fmaf(s1, sh[ 4], g);  bl = fmaf(s1, sh[ 5], bl);
                r = fmaf(c1, sh[ 6], r);  g = fmaf(c1, sh[ 7], g);  bl = fmaf(c1, sh[ 8], bl);
                r = fmaf(s2, sh[ 9], r);  g = fmaf(s2, sh[10], g);  bl = fmaf(s2, sh[11], bl);
                r = fmaf(c2, sh[12], r);  g = fmaf(c2, sh[13], g);  bl = fmaf(c2, sh[14], bl);
                r = fmaf(s3, sh[15], r);  g = fmaf(s3, sh[16], g);  bl = fmaf(s3, sh[17], bl);
                r = fmaf(c3, sh[18], r);  g = fmaf(c3, sh[19], g);  bl = fmaf(c3, sh[20], bl);
                r = fmaf(s4, sh[21], r);  g = fmaf(s4, sh[22], g);  bl = fmaf(s4, sh[23], bl);
                r = fmaf(c4, sh[24], r);  g = fmaf(c4, sh[25], g);  bl = fmaf(c4, sh[26], bl);
                r  = 1.0f / (1.0f + __expf(-r));
                g  = 1.0f / (1.0f + __expf(-g));
                bl = 1.0f / (1.0f + __expf(-bl));
                float w = __expf(-d2) * q.z;
                accR = fmaf(w, r,  accR);
                accG = fmaf(w, g,  accG);
                accB = fmaf(w, bl, accB);
            }
        }
    }

    if (b < B) {
        atomicAdd(&out[3 * b + 0], accR);
        atomicAdd(&out[3 * b + 1], accG);
        atomicAdd(&out[3 * b + 2], accB);
    }
}

extern "C" void kernel_launch(void* const* d_in, const int* in_sizes, int n_in,
                              void* d_out, int out_size, void* d_ws, size_t ws_size,
                              hipStream_t stream) {
    const float* x       = (const float*)d_in[0];
    const float* rgbsh   = (const float*)d_in[1];
    const float* opacity = (const float*)d_in[2];
    const float* mu      = (const float*)d_in[3];
    const float* scale   = (const float*)d_in[4];
    const float* angle   = (const float*)d_in[5];
    float* out = (float*)d_out;

    const int B = in_sizes[0] / 2;   // 32768
    const int N = in_sizes[2];       // 512

    // partial sums accumulate via atomics -> zero output first (graph-safe)
    hipMemsetAsync(out, 0, (size_t)out_size * sizeof(float), stream);

    dim3 grid((B + BDIM - 1) / BDIM, N / GCHUNK);
    splat_kernel<<<grid, BDIM, 0, stream>>>(x, rgbsh, opacity, mu, scale, angle,
                                            out, B, N);
}

// Round 2
// 81.749 us; speedup vs baseline: 1.0268x; 1.0268x over previous
//
#include <hip/hip_runtime.h>

#define BDIM   256
#define GCHUNK 64      // gaussians per block (N=512 / 8 chunks)
#define SHN    27      // 9 SH coeffs * 3 channels

// Each block: 256 rays x 64 gaussians. Per-gaussian derived params staged in
// LDS (broadcast reads). Wave-vote skips the heavy SH/exp body when no lane's
// ray is inside the gaussian's 5-sigma ellipse (~85% of wave-iterations).
//
// Cheap path per pair: sx = fma(pnx, ax, bx); sy = fma(pny, ay, by);
//   t = sx^2 + sy^2  ( == reference dist^2 since R is a rotation )
// Heavy path: recover pixel-space vec via vx = sx * invSx, use
//   sin(theta)=vrot_x, cos(theta)=vrot_y (|vnorm|==1 -> no atan2), harmonics
//   by angle-addition, sigmoids via v_rcp (no div sequence).
__global__ __launch_bounds__(BDIM, 4) void splat_kernel(
    const float* __restrict__ x,        // (B,2)
    const float* __restrict__ rgbsh,    // (N,9,3)
    const float* __restrict__ opacity,  // (N)
    const float* __restrict__ mu,       // (N,2)
    const float* __restrict__ scale,    // (N,2)
    const float* __restrict__ angle,    // (N)
    float* __restrict__ out,            // (B,3)
    int B, int N)
{
    __shared__ float4 gA[GCHUNK];            // ax, ay, bx, by  (affine for svec)
    __shared__ float4 gB[GCHUNK];            // cos(a), sin(a), sigmoid(op), invSx
    __shared__ float  gC[GCHUNK];            // invSy
    __shared__ float  gsh[GCHUNK][SHN];      // SH coeffs, [m*3+c]

    const int g0  = blockIdx.y * GCHUNK;
    const int tid = threadIdx.x;

    // ---- stage per-gaussian derived params ----
    if (tid < GCHUNK) {
        const int n = g0 + tid;
        const float S_MIN = 1.0f / 30.0f;
        const float S_MAX = 1.0f / 0.75f;
        float gmx = tanhf(mu[2 * n + 0]) * 1.05f;
        float gmy = tanhf(mu[2 * n + 1]) * 1.05f;
        float Sx = fminf(fmaxf(scale[2 * n + 0], 0.0f), 1.0f) * (S_MAX - S_MIN) + S_MIN;
        float Sy = fminf(fmaxf(scale[2 * n + 1], 0.0f), 1.0f) * (S_MAX - S_MIN) + S_MIN;
        // svec_x = (pnx - gmx)*256*Sx = pnx*ax + bx
        float ax = 256.0f * Sx, ay = 256.0f * Sy;
        gA[tid] = make_float4(ax, ay, -gmx * ax, -gmy * ay);
        float a = tanhf(angle[n]) * 3.1416f;
        float sa, ca;
        sincosf(a, &sa, &ca);
        float w0 = 1.0f / (1.0f + expf(-opacity[n]));
        gB[tid] = make_float4(ca, sa, w0, 1.0f / Sx);
        gC[tid] = 1.0f / Sy;
    }
    for (int i = tid; i < GCHUNK * SHN; i += BDIM)
        gsh[0][i] = rgbsh[g0 * SHN + i];
    __syncthreads();

    // ---- per-ray setup ----
    const int b  = blockIdx.x * BDIM + tid;
    const int bb = (b < B) ? b : (B - 1);          // clamp for safe loads
    // xnorm = x/512*2 - 1  (exact pow2 scaling)
    float pnx = x[2 * bb + 0] * (1.0f / 256.0f) - 1.0f;
    float pny = x[2 * bb + 1] * (1.0f / 256.0f) - 1.0f;

    float accR = 0.0f, accG = 0.0f, accB = 0.0f;

    #pragma unroll 2
    for (int j = 0; j < GCHUNK; ++j) {
        float4 p = gA[j];
        float sx = fmaf(pnx, p.x, p.z);            // scaled offset
        float sy = fmaf(pny, p.y, p.w);
        float t  = fmaf(sx, sx, sy * sy);          // == dist^2 (R is rotation)
        bool  v  = t < 25.0f;
        if (__any(v)) {
            if (v) {
                float4 q = gB[j];
                float c = q.x, s = q.y;
                // d2 via the rotated scaled vector (matches reference path)
                float rx = fmaf(c, sx, -s * sy);
                float ry = fmaf(s, sx,  c * sy);
                float d2 = fmaf(rx, rx, ry * ry);
                // pixel-space vec and its direction; |vrot|~=1 so
                // sin(theta)=vrot_x, cos(theta)=vrot_y (no atan2 needed)
                float vx  = sx * q.w;
                float vy  = sy * gC[j];
                float len = sqrtf(fmaf(vx, vx, vy * vy));
                float inv = __builtin_amdgcn_rcpf(1e-10f + len);
                float rvx = fmaf(c, vx, -s * vy);
                float rvy = fmaf(s, vx,  c * vy);
                float s1 = rvx * inv, c1 = rvy * inv;
                // harmonics by angle addition
                float s2 = 2.0f * s1 * c1;
                float c2 = fmaf(c1, c1, -s1 * s1);
                float s3 = fmaf(s2, c1,  c2 * s1);
                float c3 = fmaf(c2, c1, -s2 * s1);
                float s4 = 2.0f * s2 * c2;
                float c4 = fmaf(c2, c2, -s2 * s2);
                const float* sh = gsh[j];
                float r  = sh[0], g = sh[1], bl = sh[2];
                r = fmaf(s1, sh[ 3], r);  g = fmaf(s1, sh[ 4], g);  bl = fmaf(s1, sh[ 5], bl);
                r = fmaf(c1, sh[ 6], r);  g = fmaf(c1, sh[ 7], g);  bl = fmaf(c1, sh[ 8], bl);
                r = fmaf(s2, sh[ 9], r);  g = fmaf(s2, sh[10], g);  bl = fmaf(s2, sh[11], bl);
                r = fmaf(c2, sh[12], r);  g = fmaf(c2, sh[13], g);  bl = fmaf(c2, sh[14], bl);
                r = fmaf(s3, sh[15], r);  g = fmaf(s3, sh[16], g);  bl = fmaf(s3, sh[17], bl);
                r = fmaf(c3, sh[18], r);  g = fmaf(c3, sh[19], g);  bl = fmaf(c3, sh[20], bl);
                r = fmaf(s4, sh[21], r);  g = fmaf(s4, sh[22], g);  bl = fmaf(s4, sh[23], bl);
                r = fmaf(c4, sh[24], r);  g = fmaf(c4, sh[25], g);  bl = fmaf(c4, sh[26], bl);
                // sigmoid via v_rcp (avoid full-precision div sequence)
                r  = __builtin_amdgcn_rcpf(1.0f + __expf(-r));
                g  = __builtin_amdgcn_rcpf(1.0f + __expf(-g));
                bl = __builtin_amdgcn_rcpf(1.0f + __expf(-bl));
                float w = __expf(-d2) * q.z;
                accR = fmaf(w, r,  accR);
                accG = fmaf(w, g,  accG);
                accB = fmaf(w, bl, accB);
            }
        }
    }

    if (b < B) {
        atomicAdd(&out[3 * b + 0], accR);
        atomicAdd(&out[3 * b + 1], accG);
        atomicAdd(&out[3 * b + 2], accB);
    }
}

extern "C" void kernel_launch(void* const* d_in, const int* in_sizes, int n_in,
                              void* d_out, int out_size, void* d_ws, size_t ws_size,
                              hipStream_t stream) {
    const float* x       = (const float*)d_in[0];
    const float* rgbsh   = (const float*)d_in[1];
    const float* opacity = (const float*)d_in[2];
    const float* mu      = (const float*)d_in[3];
    const float* scale   = (const float*)d_in[4];
    const float* angle   = (const float*)d_in[5];
    float* out = (float*)d_out;

    const int B = in_sizes[0] / 2;   // 32768
    const int N = in_sizes[2];       // 512

    // partial sums accumulate via atomics -> zero output first (graph-safe)
    hipMemsetAsync(out, 0, (size_t)out_size * sizeof(float), stream);

    dim3 grid((B + BDIM - 1) / BDIM, N / GCHUNK);
    splat_kernel<<<grid, BDIM, 0, stream>>>(x, rgbsh, opacity, mu, scale, angle,
                                            out, B, N);
}